// Round 2
// baseline (5153.672 us; speedup 1.0000x reference)
//
#include <hip/hip_runtime.h>
#include <math.h>

using u16 = unsigned short;

#define TS 64
#define BKK 16

// B=8, C=512, N=4096, GP=4 -> G=32 groups, NG=1024, F=2048
constexpr int  kC     = 512;
constexpr int  kNG    = 1024;
constexpr long kPLANE = (long)kC * kNG;   // 524288 elems per (group) plane
constexpr long SZW    = (long)kC * kC;    // 262144

__device__ __forceinline__ float bf2f(u16 u) {
  return __uint_as_float(((unsigned int)u) << 16);
}
__device__ __forceinline__ u16 f2bf(float f) {
  unsigned int x = __float_as_uint(f);
  x += 0x7fffu + ((x >> 16) & 1u);       // round-to-nearest-even
  return (u16)(x >> 16);
}

// ---------------------------------------------------------------------------
// GEMM TN: Out[g][m][n] = epi( sum_k A[(g&amask)][k][m] * B[g][k][n] )
// A (K x M) bf16, B (K x Nn) bf16, Out bf16. act==1: relu+1 (phi).
// zptr: *= z[g][n] (fp32). pptr: *= p[g][m][n] (bf16, may alias Out).
// ---------------------------------------------------------------------------
__global__ __launch_bounds__(256) void gemm_tn(
    const u16* __restrict__ A, long sAg,
    const u16* __restrict__ Bm, long sBg,
    u16* Out, long sOg,
    int M, int Nn, int K, int amask, int act,
    const float* __restrict__ zptr, const u16* pptr)
{
  int g = blockIdx.z;
  const u16* Ag = A + (long)(g & amask) * sAg;
  const u16* Bg = Bm + (long)g * sBg;
  u16* Og = Out + (long)g * sOg;
  int m0 = blockIdx.y * TS, n0 = blockIdx.x * TS;
  __shared__ float As[BKK][TS];
  __shared__ float Bs[BKK][TS];
  int tid = threadIdx.x, tx = tid & 15, ty = tid >> 4;
  float acc[4][4] = {};
  int lr = tid >> 4, lc = (tid & 15) * 4;
  for (int k0 = 0; k0 < K; k0 += BKK) {
    ushort4 a4 = *(const ushort4*)&Ag[(long)(k0 + lr) * M + m0 + lc];
    *(float4*)&As[lr][lc] = make_float4(bf2f(a4.x), bf2f(a4.y), bf2f(a4.z), bf2f(a4.w));
    ushort4 b4 = *(const ushort4*)&Bg[(long)(k0 + lr) * Nn + n0 + lc];
    *(float4*)&Bs[lr][lc] = make_float4(bf2f(b4.x), bf2f(b4.y), bf2f(b4.z), bf2f(b4.w));
    __syncthreads();
#pragma unroll
    for (int kk = 0; kk < BKK; ++kk) {
      float4 a = *(const float4*)&As[kk][ty * 4];
      float4 b = *(const float4*)&Bs[kk][tx * 4];
      float av[4] = {a.x, a.y, a.z, a.w};
      float bv[4] = {b.x, b.y, b.z, b.w};
#pragma unroll
      for (int i = 0; i < 4; ++i)
#pragma unroll
        for (int j = 0; j < 4; ++j) acc[i][j] = fmaf(av[i], bv[j], acc[i][j]);
    }
    __syncthreads();
  }
#pragma unroll
  for (int i = 0; i < 4; ++i) {
    int m = m0 + ty * 4 + i;
    u16 rv[4];
#pragma unroll
    for (int j = 0; j < 4; ++j) {
      int n = n0 + tx * 4 + j;
      float v = acc[i][j];
      if (act == 1) v = fmaxf(v, 0.f) + 1.f;
      if (zptr) v *= zptr[(long)g * Nn + n];
      if (pptr) v *= bf2f(pptr[(long)g * sOg + (long)m * Nn + n]);
      rv[j] = f2bf(v);
    }
    ushort4 r; r.x = rv[0]; r.y = rv[1]; r.z = rv[2]; r.w = rv[3];
    *(ushort4*)&Og[(long)m * Nn + n0 + tx * 4] = r;
  }
}

// ---------------------------------------------------------------------------
// GEMM NT: Out[g][m][n] = epi( scale * sum_k (A[g][m][k]*alpha?[g][k]) * B[g][n][k] )
// A (M x K) bf16, B (Nn x K) bf16, Out bf16. bias fp32, resid bf16, act=relu.
// ---------------------------------------------------------------------------
__global__ __launch_bounds__(256) void gemm_nt(
    const u16* __restrict__ A, long sAg,
    const u16* __restrict__ Bm, long sBg,
    u16* Out, long sOg,
    int M, int Nn, int K,
    const float* __restrict__ alpha, float scale,
    const float* __restrict__ bias, const u16* resid, int act)
{
  int g = blockIdx.z;
  const u16* Ag = A + (long)g * sAg;
  const u16* Bg = Bm + (long)g * sBg;
  u16* Og = Out + (long)g * sOg;
  int m0 = blockIdx.y * TS, n0 = blockIdx.x * TS;
  __shared__ float As[BKK][68];
  __shared__ float Bs[BKK][68];
  __shared__ float alph[BKK];
  int tid = threadIdx.x, tx = tid & 15, ty = tid >> 4;
  float acc[4][4] = {};
  int lr = tid >> 2, lk = (tid & 3) * 4;
  for (int k0 = 0; k0 < K; k0 += BKK) {
    ushort4 a4 = *(const ushort4*)&Ag[(long)(m0 + lr) * K + k0 + lk];
    As[lk + 0][lr] = bf2f(a4.x); As[lk + 1][lr] = bf2f(a4.y);
    As[lk + 2][lr] = bf2f(a4.z); As[lk + 3][lr] = bf2f(a4.w);
    ushort4 b4 = *(const ushort4*)&Bg[(long)(n0 + lr) * K + k0 + lk];
    Bs[lk + 0][lr] = bf2f(b4.x); Bs[lk + 1][lr] = bf2f(b4.y);
    Bs[lk + 2][lr] = bf2f(b4.z); Bs[lk + 3][lr] = bf2f(b4.w);
    if (tid < BKK) alph[tid] = alpha ? alpha[(long)g * K + k0 + tid] : 1.f;
    __syncthreads();
#pragma unroll
    for (int kk = 0; kk < BKK; ++kk) {
      float4 a = *(const float4*)&As[kk][ty * 4];
      float4 b = *(const float4*)&Bs[kk][tx * 4];
      if (alpha) { float al = alph[kk]; a.x *= al; a.y *= al; a.z *= al; a.w *= al; }
      float av2[4] = {a.x, a.y, a.z, a.w};
      float bv2[4] = {b.x, b.y, b.z, b.w};
#pragma unroll
      for (int i = 0; i < 4; ++i)
#pragma unroll
        for (int j = 0; j < 4; ++j) acc[i][j] = fmaf(av2[i], bv2[j], acc[i][j]);
    }
    __syncthreads();
  }
#pragma unroll
  for (int i = 0; i < 4; ++i) {
    int m = m0 + ty * 4 + i;
    u16 rv[4];
#pragma unroll
    for (int j = 0; j < 4; ++j) {
      int n = n0 + tx * 4 + j;
      float v = acc[i][j] * scale;
      if (bias) v += bias[n];
      if (resid) v += bf2f(resid[(long)g * sOg + (long)m * Nn + n]);
      if (act == 1) v = fmaxf(v, 0.f);
      rv[j] = f2bf(v);
    }
    ushort4 r; r.x = rv[0]; r.y = rv[1]; r.z = rv[2]; r.w = rv[3];
    *(ushort4*)&Og[(long)m * Nn + n0 + tx * 4] = r;
  }
}

// Weight transpose 512x512: Out[c][d] = f2bf(X[d][c]). block(32,8)
__global__ __launch_bounds__(256) void transpose_f2b(
    const float* __restrict__ X, u16* __restrict__ Out)
{
  __shared__ float t[32][33];
  int i0 = blockIdx.y * 32, j0 = blockIdx.x * 32;
  int tx = threadIdx.x, ty = threadIdx.y;
  for (int r = ty; r < 32; r += 8) t[r][tx] = X[(long)(i0 + r) * 512 + j0 + tx];
  __syncthreads();
  for (int r = ty; r < 32; r += 8) Out[(long)(j0 + r) * 512 + i0 + tx] = f2bf(t[tx][r]);
}

// Out[g][j][i] = X[g][i][j] + (Y ? Y[g][i][j] : 0), bf16 in/out. block(32,8)
__global__ __launch_bounds__(256) void transpose_add_b(
    const u16* __restrict__ X, const u16* __restrict__ Y,
    u16* __restrict__ Out, int R, int Cn)
{
  int g = blockIdx.z;
  const u16* Xg = X + (long)g * R * Cn;
  const u16* Yg = Y ? Y + (long)g * R * Cn : nullptr;
  u16* Og = Out + (long)g * R * Cn;
  __shared__ float t[32][33];
  int i0 = blockIdx.y * 32, j0 = blockIdx.x * 32;
  int tx = threadIdx.x, ty = threadIdx.y;
  for (int r = ty; r < 32; r += 8) {
    float v = bf2f(Xg[(long)(i0 + r) * Cn + j0 + tx]);
    if (Yg) v += bf2f(Yg[(long)(i0 + r) * Cn + j0 + tx]);
    t[r][tx] = v;
  }
  __syncthreads();
  for (int r = ty; r < 32; r += 8)
    Og[(long)(j0 + r) * R + i0 + tx] = f2bf(t[tx][r]);
}

// out[g][c] = scale * sum_n X[g][c][n] * alpha?[g][n]. X bf16. grid(Cn, G)
__global__ __launch_bounds__(256) void rowreduce(
    const u16* __restrict__ X, const float* __restrict__ alpha,
    float* __restrict__ out, int Cn, int Nn, float scale)
{
  int c = blockIdx.x, g = blockIdx.y, tid = threadIdx.x;
  const u16* row = X + ((long)g * Cn + c) * Nn;
  float s = 0.f;
  for (int n = tid; n < Nn; n += 256)
    s += bf2f(row[n]) * (alpha ? alpha[(long)g * Nn + n] : 1.f);
  __shared__ float red[256];
  red[tid] = s; __syncthreads();
  for (int st = 128; st; st >>= 1) { if (tid < st) red[tid] += red[tid + st]; __syncthreads(); }
  if (tid == 0) out[(long)g * Cn + c] = red[0] * scale;
}

// out[g][n] = f( sum_c w[(g&wmask)][c] * X[g][c][n] ). X bf16. mode1: 1/(x+1e-6)
__global__ __launch_bounds__(256) void colreduce(
    const u16* __restrict__ X, const float* __restrict__ w,
    float* __restrict__ out, int Cn, int Nn, int wmask, int mode)
{
  int g = blockIdx.y, tid = threadIdx.x;
  long n = (long)blockIdx.x * 256 + tid;
  __shared__ float ws_[512];
  for (int c = tid; c < Cn; c += 256) ws_[c] = w[(long)(g & wmask) * Cn + c];
  __syncthreads();
  const u16* Xg = X + (long)g * Cn * Nn;
  float s = 0.f;
  for (int c = 0; c < Cn; ++c) s += bf2f(Xg[(long)c * Nn + n]) * ws_[c];
  if (mode == 1) s = 1.f / (s + 1e-6f);
  out[(long)g * Nn + n] = s;
}

// alpha[g][n] = softmax_n(sc[g])[n] * Nn. fp32. grid(G)
__global__ __launch_bounds__(256) void softmax_row(
    const float* __restrict__ sc, float* __restrict__ out, int Nn)
{
  int g = blockIdx.x, tid = threadIdx.x;
  const float* s = sc + (long)g * Nn;
  float* o = out + (long)g * Nn;
  __shared__ float red[256];
  float lm = -3.4e38f;
  for (int n = tid; n < Nn; n += 256) lm = fmaxf(lm, s[n]);
  red[tid] = lm; __syncthreads();
  for (int st = 128; st; st >>= 1) { if (tid < st) red[tid] = fmaxf(red[tid], red[tid + st]); __syncthreads(); }
  float mx = red[0]; __syncthreads();
  float ls = 0.f;
  for (int n = tid; n < Nn; n += 256) ls += __expf(s[n] - mx);
  red[tid] = ls; __syncthreads();
  for (int st = 128; st; st >>= 1) { if (tid < st) red[tid] += red[tid + st]; __syncthreads(); }
  float inv = (float)Nn / red[0];
  for (int n = tid; n < Nn; n += 256) o[n] = __expf(s[n] - mx) * inv;
}

// LayerNorm over 512-wide contiguous rows, bf16 in/out, fp32 gamma/beta.
__global__ __launch_bounds__(256) void ln_rows(
    const u16* __restrict__ X, const float* __restrict__ gamma,
    const float* __restrict__ beta, u16* __restrict__ Out, int relu)
{
  long m = blockIdx.x;
  const u16* x = X + m * 512;
  u16* o = Out + m * 512;
  int tid = threadIdx.x;
  ushort2 u2 = *(const ushort2*)&x[tid * 2];
  float v0 = bf2f(u2.x), v1 = bf2f(u2.y);
  __shared__ float red[256];
  red[tid] = v0 + v1; __syncthreads();
  for (int st = 128; st; st >>= 1) { if (tid < st) red[tid] += red[tid + st]; __syncthreads(); }
  float mu = red[0] * (1.f / 512.f);
  __syncthreads();
  float d0 = v0 - mu, d1 = v1 - mu;
  red[tid] = d0 * d0 + d1 * d1; __syncthreads();
  for (int st = 128; st; st >>= 1) { if (tid < st) red[tid] += red[tid + st]; __syncthreads(); }
  float rs = rsqrtf(red[0] * (1.f / 512.f) + 1e-6f);
  float2 gm = *(const float2*)&gamma[tid * 2];
  float2 bt = *(const float2*)&beta[tid * 2];
  float o0 = d0 * rs * gm.x + bt.x, o1 = d1 * rs * gm.y + bt.y;
  if (relu) { o0 = fmaxf(o0, 0.f); o1 = fmaxf(o1, 0.f); }
  ushort2 r; r.x = f2bf(o0); r.y = f2bf(o1);
  *(ushort2*)&o[tid * 2] = r;
}

// gx[g=gp*8+b][c][n] = feat[b][c][n*4+gp]   (fp32 -> bf16)
__global__ __launch_bounds__(256) void gather_xsa(
    const float* __restrict__ feat, u16* __restrict__ X)
{
  long idx = (long)blockIdx.x * 256 + threadIdx.x;
  int n = (int)(idx & 1023);
  int c = (int)((idx >> 10) & 511);
  int g = (int)(idx >> 19);
  int gp = g >> 3, b = g & 7;
  X[idx] = f2bf(feat[((long)b * 512 + c) * 4096 + n * 4 + gp]);
}

// gx2[g2=gp2*8+b][c][m] = t_sa[(m&3)*8+b][c][gp2*256+(m>>2)]. grid(4,512,32)
__global__ __launch_bounds__(256) void gather_x2(
    const u16* __restrict__ T, u16* __restrict__ X2)
{
  int g2 = blockIdx.z, c = blockIdx.y, m0 = blockIdx.x * 256;
  int gp2 = g2 >> 3, b = g2 & 7;
  __shared__ u16 s[256];
  int t = threadIdx.x;
  int p = t >> 6, off = t & 63;
  s[off * 4 + p] = T[((long)(p * 8 + b) * 512 + c) * 1024 + gp2 * 256 + (m0 >> 2) + off];
  __syncthreads();
  X2[((long)g2 * 512 + c) * 1024 + m0 + t] = s[t];
}

// ybar[d][n] = mean over 24 rest groups (bf16 in, fp32 out)
__global__ __launch_bounds__(256) void ybar_k(
    const u16* __restrict__ Y, float* __restrict__ yb)
{
  long idx = (long)blockIdx.x * 256 + threadIdx.x;
  float s = 0.f;
#pragma unroll
  for (int g = 0; g < 24; ++g) s += bf2f(Y[(long)g * kPLANE + idx]);
  yb[idx] = s * (1.f / 24.f);
}

// yf[b][d][n] = ybar[d][n] * phi_first[b][d][n]
__global__ __launch_bounds__(256) void yfirst_k(
    const float* __restrict__ yb, const u16* __restrict__ pf, u16* __restrict__ yf)
{
  long idx = (long)blockIdx.x * 256 + threadIdx.x;
  yf[idx] = f2bf(yb[idx & (kPLANE - 1)] * bf2f(pf[idx]));
}

// out[b][c][gp2*1024+m] = gp2==0 ? crossT[b][c][m] : X2[gp2*8+b][c][m]  (fp32 out)
__global__ __launch_bounds__(256) void assemble(
    const u16* __restrict__ X2, const u16* __restrict__ COT, float* __restrict__ out)
{
  long idx = (long)blockIdx.x * 256 + threadIdx.x;
  int n = (int)(idx & 4095);
  int c = (int)((idx >> 12) & 511);
  int b = (int)(idx >> 21);
  int gp2 = n >> 10, m = n & 1023;
  float v;
  if (gp2 == 0) v = bf2f(COT[((long)b * 512 + c) * 1024 + m]);
  else          v = bf2f(X2[((long)(gp2 * 8 + b) * 512 + c) * 1024 + m]);
  out[idx] = v;
}

// fp32 -> bf16 flat cast
__global__ __launch_bounds__(256) void castf2b(
    const float* __restrict__ src, u16* __restrict__ dst, int n)
{
  int i = blockIdx.x * 256 + threadIdx.x;
  if (i < n) dst[i] = f2bf(src[i]);
}

extern "C" void kernel_launch(void* const* d_in, const int* in_sizes, int n_in,
                              void* d_out, int out_size, void* d_ws, size_t ws_size,
                              hipStream_t stream)
{
  const float* feat = (const float*)d_in[0];
  const float* tg1 = (const float*)d_in[4];  const float* tb1 = (const float*)d_in[5];
  const float* tf1w = (const float*)d_in[6]; const float* tf1b = (const float*)d_in[7];
  const float* tf2w = (const float*)d_in[8]; const float* tf2b = (const float*)d_in[9];
  const float* tg2 = (const float*)d_in[10]; const float* tb2 = (const float*)d_in[11];
  const float* cg1 = (const float*)d_in[16]; const float* cb1 = (const float*)d_in[17];
  const float* cf1w = (const float*)d_in[18]; const float* cf1b = (const float*)d_in[19];
  const float* cf2w = (const float*)d_in[20]; const float* cf2b = (const float*)d_in[21];
  const float* cg2 = (const float*)d_in[22]; const float* cb2 = (const float*)d_in[23];

  // ---- workspace layout (byte offsets; peak ~115 MB) ----
  char* wsb = (char*)d_ws;
  u16* WT = (u16*)(wsb);                    // 7 * 262144 bf16 = 3.67 MB
  u16* WF = (u16*)(wsb + (4l  << 20));      // 4 * 1048576 bf16 = 8.39 MB
  u16* Xb = (u16*)(wsb + (16l << 20));      // 32 planes bf16 = 33.55 MB
  u16* Qb = (u16*)(wsb + (48l << 20));
  u16* Vb = (u16*)(wsb + (80l << 20));
  float* SM = (float*)(wsb + (112l << 20)); // smalls, fp32, ~2.72 MB
  float* QG = SM;             // 32*512
  float* SC = SM + 16384;     // 32*1024
  float* AL = SM + 49152;     // 32*1024
  float* KS = SM + 81920;     // 32*512
  float* Zb = SM + 98304;     // 32*1024
  float* ZR = SM + 131072;    // 24*1024
  float* YB = SM + 155648;    // 512*1024 fp32

  // ---- d_out doubles as scratch until the final assemble ----
  char* outb = (char*)d_out;
  u16* KV  = (u16*)outb;                 // SA kv: 32*SZW bf16 = 16.8 MB
  u16* HID = (u16*)outb;                 // FFN hidden chunk (kv dead by then)
  u16* PR  = (u16*)outb;                 // cross phi_rest / y_rest: 24 planes
  u16* KV2 = (u16*)(outb + (32l << 20)); // cross kv: 8*SZW bf16

  u16 *WTQK = WT,           *WTV  = WT + SZW,     *WTPHI = WT + 2 * SZW,
      *WTCQ = WT + 3 * SZW, *WTCK = WT + 4 * SZW, *WTCV  = WT + 5 * SZW,
      *WTCPHI = WT + 6 * SZW;
  u16 *WF1 = WF, *WF2 = WF + 1048576, *WFC1 = WF + 2097152, *WFC2 = WF + 3145728;

  dim3 b256(256), bT(32, 8);
  const float rsc = 1.0f / sqrtf(512.0f);
  const long PL = kPLANE;

  // 0. weight prep: transpose projections, cast FFN weights
  const float* wsrc[7] = {(const float*)d_in[1], (const float*)d_in[2], (const float*)d_in[3],
                          (const float*)d_in[12], (const float*)d_in[13], (const float*)d_in[14],
                          (const float*)d_in[15]};
  for (int i = 0; i < 7; ++i)
    transpose_f2b<<<dim3(16, 16, 1), bT, 0, stream>>>(wsrc[i], WT + i * SZW);
  castf2b<<<4096, b256, 0, stream>>>(tf1w, WF1, 1048576);
  castf2b<<<4096, b256, 0, stream>>>(tf2w, WF2, 1048576);
  castf2b<<<4096, b256, 0, stream>>>(cf1w, WFC1, 1048576);
  castf2b<<<4096, b256, 0, stream>>>(cf2w, WFC2, 1048576);

  // ---------------- SA block ----------------
  gather_xsa<<<65536, b256, 0, stream>>>(feat, Xb);
  // q = phi(Wqk x)
  gemm_tn<<<dim3(16, 8, 32), b256, 0, stream>>>(WTQK, 0, Xb, PL, Qb, PL, 512, kNG, 512, 0, 1, nullptr, nullptr);
  // alpha chain
  rowreduce<<<dim3(512, 32), b256, 0, stream>>>(Qb, nullptr, QG, 512, kNG, 1.f / 1024.f);
  colreduce<<<dim3(4, 32), b256, 0, stream>>>(Qb, QG, SC, 512, kNG, 31, 0);
  softmax_row<<<32, b256, 0, stream>>>(SC, AL, kNG);
  // v, then kv = (q*alpha) v^T / sqrt(C)
  gemm_tn<<<dim3(16, 8, 32), b256, 0, stream>>>(WTV, 0, Xb, PL, Vb, PL, 512, kNG, 512, 0, 0, nullptr, nullptr);
  gemm_nt<<<dim3(8, 8, 32), b256, 0, stream>>>(Qb, PL, Vb, PL, KV, SZW, 512, 512, kNG, AL, rsc, nullptr, nullptr, 0);
  // ksum, z
  rowreduce<<<dim3(512, 32), b256, 0, stream>>>(Qb, AL, KS, 512, kNG, 1.f);
  colreduce<<<dim3(4, 32), b256, 0, stream>>>(Qb, KS, Zb, 512, kNG, 31, 1);
  // phix overwrites v; y = (kv^T q) * z * phix in-place
  gemm_tn<<<dim3(16, 8, 32), b256, 0, stream>>>(WTPHI, 0, Xb, PL, Vb, PL, 512, kNG, 512, 0, 0, nullptr, nullptr);
  gemm_tn<<<dim3(16, 8, 32), b256, 0, stream>>>(KV, SZW, Qb, PL, Vb, PL, 512, kNG, 512, 31, 0, Zb, Vb);
  // h_pre = (x+y)^T -> Qb; LN1 -> Xb
  transpose_add_b<<<dim3(32, 16, 32), bT, 0, stream>>>(Xb, Vb, Qb, 512, 1024);
  ln_rows<<<32768, b256, 0, stream>>>(Qb, tg1, tb1, Xb, 0);
  // FFN 512->2048->512 (+bias +residual), 4 chunks of 8192 rows
  for (int ch = 0; ch < 4; ++ch) {
    const u16* Hc = Xb + (long)ch * 8192 * 512;
    gemm_nt<<<dim3(32, 128, 1), b256, 0, stream>>>(Hc, 0, WF1, 0, HID, 0, 8192, 2048, 512,
                                                   nullptr, 1.f, tf1b, nullptr, 1);
    gemm_nt<<<dim3(8, 128, 1), b256, 0, stream>>>(HID, 0, WF2, 0, Qb + (long)ch * 8192 * 512, 0,
                                                  8192, 512, 2048, nullptr, 1.f, tf2b, Hc, 0);
  }
  // LN2+relu -> Vb (g,n,c); transpose -> Qb = t_sa (g,c,n); gather -> Xb = gx2
  ln_rows<<<32768, b256, 0, stream>>>(Qb, tg2, tb2, Vb, 1);
  transpose_add_b<<<dim3(16, 32, 32), bT, 0, stream>>>(Vb, nullptr, Qb, 1024, 512);
  gather_x2<<<dim3(4, 512, 32), b256, 0, stream>>>(Qb, Xb);

  // ---------------- cross block ----------------
  u16 *V0 = Vb, *V1 = Vb + 8 * PL, *V2 = Vb + 16 * PL, *V3 = Vb + 24 * PL;
  gemm_tn<<<dim3(16, 8, 24), b256, 0, stream>>>(WTCQ, 0, Xb + 8 * PL, PL, Qb, PL, 512, kNG, 512, 0, 1, nullptr, nullptr); // q_rest
  gemm_tn<<<dim3(16, 8, 24), b256, 0, stream>>>(WTCPHI, 0, Xb + 8 * PL, PL, PR, PL, 512, kNG, 512, 0, 0, nullptr, nullptr); // phi_rest
  gemm_tn<<<dim3(16, 8, 8), b256, 0, stream>>>(WTCK, 0, Xb, PL, V0, PL, 512, kNG, 512, 0, 1, nullptr, nullptr); // k0
  gemm_tn<<<dim3(16, 8, 8), b256, 0, stream>>>(WTCV, 0, Xb, PL, V1, PL, 512, kNG, 512, 0, 0, nullptr, nullptr); // v0
  gemm_tn<<<dim3(16, 8, 8), b256, 0, stream>>>(WTCPHI, 0, Xb, PL, V2, PL, 512, kNG, 512, 0, 0, nullptr, nullptr); // phi_first
  // per-b alpha/kv/ksum
  rowreduce<<<dim3(512, 8), b256, 0, stream>>>(V0, nullptr, QG, 512, kNG, 1.f / 1024.f);
  colreduce<<<dim3(4, 8), b256, 0, stream>>>(V0, QG, SC, 512, kNG, 7, 0);
  softmax_row<<<8, b256, 0, stream>>>(SC, AL, kNG);
  gemm_nt<<<dim3(8, 8, 8), b256, 0, stream>>>(V0, PL, V1, PL, KV2, SZW, 512, 512, kNG, AL, rsc, nullptr, nullptr, 0);
  rowreduce<<<dim3(512, 8), b256, 0, stream>>>(V0, AL, KS, 512, kNG, 1.f);
  // z for 24 rest groups; y_rest in-place into PR
  colreduce<<<dim3(4, 24), b256, 0, stream>>>(Qb, KS, ZR, 512, kNG, 7, 1);
  gemm_tn<<<dim3(16, 8, 24), b256, 0, stream>>>(KV2, SZW, Qb, PL, PR, PL, 512, kNG, 512, 7, 0, ZR, PR);
  // y_first = mean(y_rest) * phi_first
  ybar_k<<<2048, b256, 0, stream>>>(PR, YB);
  yfirst_k<<<16384, b256, 0, stream>>>(YB, V2, V3);
  // FFN-LN on the 8 first groups
  transpose_add_b<<<dim3(32, 16, 8), bT, 0, stream>>>(Xb, V3, V0, 512, 1024);
  ln_rows<<<8192, b256, 0, stream>>>(V0, cg1, cb1, V1, 0);
  gemm_nt<<<dim3(32, 128, 1), b256, 0, stream>>>(V1, 0, WFC1, 0, HID, 0, 8192, 2048, 512,
                                                 nullptr, 1.f, cf1b, nullptr, 1);
  gemm_nt<<<dim3(8, 128, 1), b256, 0, stream>>>(HID, 0, WFC2, 0, V2, 0, 8192, 512, 2048,
                                                nullptr, 1.f, cf2b, V1, 0);
  ln_rows<<<8192, b256, 0, stream>>>(V2, cg2, cb2, V3, 1);
  transpose_add_b<<<dim3(16, 32, 8), bT, 0, stream>>>(V3, nullptr, V0, 1024, 512);
  // final assembly: gp2==0 from cross output, gp2>=1 passthrough from gx2
  assemble<<<65536, b256, 0, stream>>>(Xb, V0, (float*)d_out);
}

// Round 3
// 1788.978 us; speedup vs baseline: 2.8808x; 2.8808x over previous
//
#include <hip/hip_runtime.h>
#include <math.h>

using u16 = unsigned short;
typedef __attribute__((ext_vector_type(8))) short short8;
typedef __attribute__((ext_vector_type(4))) float f32x4;

// B=8, C=512, N=4096, GP=4 -> G=32 groups, NG=1024, F=2048
constexpr long kPLANE = 1024l * 512;     // elems per (g) plane, T-layout (n, c)
constexpr long SZW    = 512l * 512;
constexpr long MB     = 1l << 20;

__device__ __forceinline__ float bf2f(u16 u) {
  return __uint_as_float(((unsigned int)u) << 16);
}
__device__ __forceinline__ u16 f2bf(float f) {
  unsigned int x = __float_as_uint(f);
  x += 0x7fffu + ((x >> 16) & 1u);
  return (u16)(x >> 16);
}

// ---------------------------------------------------------------------------
// Unified MFMA GEMM (NT form): Out[g][m][n] = epi( scale * sum_k A[m][k]*B[n][k] )
// A (M x K) bf16 K-contig, B (N x K) bf16 K-contig. 128x128 tile, BK=32,
// 4 waves each 64x64 via 4x4 v_mfma_f32_16x16x32_bf16.
// epi: *rowscale[g][m] -> *pmul[g][m][n] -> +bias[n] -> +resid[g][m][n] -> act
// act: 0 none, 1 relu, 2 relu+1 (phi). pmul may alias Out.
// ---------------------------------------------------------------------------
__global__ __launch_bounds__(256) void gemm_mfma(
    const u16* __restrict__ A, long sA, int amask,
    const u16* __restrict__ B, long sB, int bmask,
    u16* __restrict__ Out, long sO,
    int M, int Nn, int K, float scale, int act,
    const float* __restrict__ bias,
    const float* __restrict__ rowscale, long sRS,
    const u16* __restrict__ pmul, const u16* __restrict__ resid)
{
  int g = blockIdx.z;
  const u16* Ag = A + (long)(g & amask) * sA;
  const u16* Bg = B + (long)(g & bmask) * sB;
  u16* Og = Out + (long)g * sO;
  int m0 = blockIdx.y * 128, n0 = blockIdx.x * 128;

  __shared__ __align__(16) u16 As[128 * 32];
  __shared__ __align__(16) u16 Bs[128 * 32];

  int tid = threadIdx.x;
  int w = tid >> 6, L = tid & 63;
  int wm = (w >> 1) * 64, wn = (w & 1) * 64;
  int l15 = L & 15, l4 = L >> 4;

  f32x4 acc[4][4] = {};

  // staging assignment: 512 16B-chunks per tile, 2 per thread per tile
  int q0 = tid, q1 = tid + 256;
  int r0 = q0 >> 2, kk0 = (q0 & 3) * 8;
  int r1 = q1 >> 2, kk1 = (q1 & 3) * 8;

  for (int k0 = 0; k0 < K; k0 += 32) {
    *(short8*)&As[r0 * 32 + kk0] = *(const short8*)&Ag[(long)(m0 + r0) * K + k0 + kk0];
    *(short8*)&As[r1 * 32 + kk1] = *(const short8*)&Ag[(long)(m0 + r1) * K + k0 + kk1];
    *(short8*)&Bs[r0 * 32 + kk0] = *(const short8*)&Bg[(long)(n0 + r0) * K + k0 + kk0];
    *(short8*)&Bs[r1 * 32 + kk1] = *(const short8*)&Bg[(long)(n0 + r1) * K + k0 + kk1];
    __syncthreads();
    short8 af[4], bf[4];
#pragma unroll
    for (int mi = 0; mi < 4; ++mi)
      af[mi] = *(const short8*)&As[(wm + mi * 16 + l15) * 32 + l4 * 8];
#pragma unroll
    for (int ni = 0; ni < 4; ++ni)
      bf[ni] = *(const short8*)&Bs[(wn + ni * 16 + l15) * 32 + l4 * 8];
#pragma unroll
    for (int mi = 0; mi < 4; ++mi)
#pragma unroll
      for (int ni = 0; ni < 4; ++ni)
        acc[mi][ni] = __builtin_amdgcn_mfma_f32_16x16x32_bf16(af[mi], bf[ni], acc[mi][ni], 0, 0, 0);
    __syncthreads();
  }

  // epilogue. C/D layout: col = L&15, row = (L>>4)*4 + r   [measured m89/m91]
#pragma unroll
  for (int mi = 0; mi < 4; ++mi) {
#pragma unroll
    for (int r = 0; r < 4; ++r) {
      int m = m0 + wm + mi * 16 + l4 * 4 + r;
      float rs = rowscale ? rowscale[(long)g * sRS + m] : 1.f;
#pragma unroll
      for (int ni = 0; ni < 4; ++ni) {
        int n = n0 + wn + ni * 16 + l15;
        float v = acc[mi][ni][r] * scale * rs;
        if (pmul)  v *= bf2f(pmul[(long)g * sO + (long)m * Nn + n]);
        if (bias)  v += bias[n];
        if (resid) v += bf2f(resid[(long)g * sO + (long)m * Nn + n]);
        if (act == 1) v = fmaxf(v, 0.f);
        else if (act == 2) v = fmaxf(v, 0.f) + 1.f;
        Og[(long)m * Nn + n] = f2bf(v);
      }
    }
  }
}

// fp32 -> bf16 flat cast
__global__ __launch_bounds__(256) void castf2b(
    const float* __restrict__ src, u16* __restrict__ dst, int n)
{
  int i = blockIdx.x * 256 + threadIdx.x;
  if (i < n) dst[i] = f2bf(src[i]);
}

// gxT[gp*8+b][n][c] = feat[b][c][4n+gp]  (fp32 -> bf16). grid(32,16,8) block(32,8)
__global__ __launch_bounds__(256) void gather_feat(
    const float* __restrict__ feat, u16* __restrict__ gxT)
{
  __shared__ float t[32][132];
  int b = blockIdx.z, c0 = blockIdx.y * 32, nf0 = blockIdx.x * 128;
  int tx = threadIdx.x, ty = threadIdx.y;
  for (int r = ty; r < 32; r += 8)
    *(float4*)&t[r][tx * 4] = *(const float4*)&feat[((long)b * 512 + c0 + r) * 4096 + nf0 + tx * 4];
  __syncthreads();
  int n0o = nf0 >> 2;
  for (int gp = 0; gp < 4; ++gp) {
    long gbase = (long)(gp * 8 + b) * kPLANE;
    for (int jr = ty; jr < 32; jr += 8)
      gxT[gbase + (long)(n0o + jr) * 512 + c0 + tx] = f2bf(t[tx][jr * 4 + gp]);
  }
}

// out[g][c][n] = in[g][n][c] * (alpha ? alpha[g][n] : 1). grid(32,16,G) block(32,8)
__global__ __launch_bounds__(256) void transpose_b(
    const u16* __restrict__ in, u16* __restrict__ out, const float* __restrict__ alpha)
{
  int g = blockIdx.z;
  const u16* I = in + (long)g * kPLANE;
  u16* O = out + (long)g * kPLANE;
  __shared__ u16 t[32][33];
  int n0 = blockIdx.x * 32, c0 = blockIdx.y * 32;
  int tx = threadIdx.x, ty = threadIdx.y;
  for (int r = ty; r < 32; r += 8) t[r][tx] = I[(long)(n0 + r) * 512 + c0 + tx];
  __syncthreads();
  float al = alpha ? alpha[(long)g * 1024 + n0 + tx] : 1.f;
  for (int r = ty; r < 32; r += 8)
    O[(long)(c0 + r) * 1024 + n0 + tx] = f2bf(bf2f(t[tx][r]) * al);
}

// out[g][c] = scale * sum_n X[g][n][c] * (alpha ? alpha[g][n] : 1). grid(2,G)
__global__ __launch_bounds__(256) void colsum(
    const u16* __restrict__ X, long sX, const float* __restrict__ alpha,
    float* __restrict__ out, float scale)
{
  int g = blockIdx.y;
  int c = blockIdx.x * 256 + threadIdx.x;
  const u16* Xg = X + (long)g * sX;
  float s = 0.f;
  for (int n = 0; n < 1024; ++n)
    s += bf2f(Xg[(long)n * 512 + c]) * (alpha ? alpha[(long)g * 1024 + n] : 1.f);
  out[(long)g * 512 + c] = s * scale;
}

// out[g][n] = f( sum_c X[g][n][c] * w[(g&wmask)][c] ). mode1: 1/(x+1e-6). grid(256,G)
__global__ __launch_bounds__(256) void rowdot(
    const u16* __restrict__ X, long sX, const float* __restrict__ w, int wmask,
    float* __restrict__ out, int mode)
{
  int g = blockIdx.y;
  int n = blockIdx.x * 4 + (threadIdx.x >> 6);
  int L = threadIdx.x & 63;
  const u16* row = X + (long)g * sX + (long)n * 512;
  short8 xv = *(const short8*)&row[L * 8];
  const float* wg = w + (long)(g & wmask) * 512;
  float4 w0 = *(const float4*)&wg[L * 8];
  float4 w1 = *(const float4*)&wg[L * 8 + 4];
  float s = bf2f((u16)xv[0]) * w0.x + bf2f((u16)xv[1]) * w0.y +
            bf2f((u16)xv[2]) * w0.z + bf2f((u16)xv[3]) * w0.w +
            bf2f((u16)xv[4]) * w1.x + bf2f((u16)xv[5]) * w1.y +
            bf2f((u16)xv[6]) * w1.z + bf2f((u16)xv[7]) * w1.w;
#pragma unroll
  for (int off = 32; off >= 1; off >>= 1) s += __shfl_down(s, off);
  if (L == 0) out[(long)g * 1024 + n] = mode ? 1.f / (s + 1e-6f) : s;
}

// alpha[g][n] = softmax_n(sc[g])[n] * 1024. grid(G)
__global__ __launch_bounds__(256) void softmax_row(
    const float* __restrict__ sc, float* __restrict__ out)
{
  int g = blockIdx.x, tid = threadIdx.x;
  const float* s = sc + (long)g * 1024;
  float* o = out + (long)g * 1024;
  __shared__ float red[256];
  float lm = -3.4e38f;
  for (int n = tid; n < 1024; n += 256) lm = fmaxf(lm, s[n]);
  red[tid] = lm; __syncthreads();
  for (int st = 128; st; st >>= 1) { if (tid < st) red[tid] = fmaxf(red[tid], red[tid + st]); __syncthreads(); }
  float mx = red[0]; __syncthreads();
  float ls = 0.f;
  for (int n = tid; n < 1024; n += 256) ls += __expf(s[n] - mx);
  red[tid] = ls; __syncthreads();
  for (int st = 128; st; st >>= 1) { if (tid < st) red[tid] += red[tid + st]; __syncthreads(); }
  float inv = 1024.f / red[0];
  for (int n = tid; n < 1024; n += 256) o[n] = __expf(s[n] - mx) * inv;
}

// LayerNorm over 512-wide contiguous rows, bf16 in/out, fp32 gamma/beta.
__global__ __launch_bounds__(256) void ln_rows(
    const u16* __restrict__ X, const float* __restrict__ gamma,
    const float* __restrict__ beta, u16* __restrict__ Out, int relu)
{
  long m = blockIdx.x;
  const u16* x = X + m * 512;
  u16* o = Out + m * 512;
  int tid = threadIdx.x;
  ushort2 u2 = *(const ushort2*)&x[tid * 2];
  float v0 = bf2f(u2.x), v1 = bf2f(u2.y);
  __shared__ float red[256];
  red[tid] = v0 + v1; __syncthreads();
  for (int st = 128; st; st >>= 1) { if (tid < st) red[tid] += red[tid + st]; __syncthreads(); }
  float mu = red[0] * (1.f / 512.f);
  __syncthreads();
  float d0 = v0 - mu, d1 = v1 - mu;
  red[tid] = d0 * d0 + d1 * d1; __syncthreads();
  for (int st = 128; st; st >>= 1) { if (tid < st) red[tid] += red[tid + st]; __syncthreads(); }
  float rs = rsqrtf(red[0] * (1.f / 512.f) + 1e-6f);
  float2 gm = *(const float2*)&gamma[tid * 2];
  float2 bt = *(const float2*)&beta[tid * 2];
  float o0 = d0 * rs * gm.x + bt.x, o1 = d1 * rs * gm.y + bt.y;
  if (relu) { o0 = fmaxf(o0, 0.f); o1 = fmaxf(o1, 0.f); }
  ushort2 r; r.x = f2bf(o0); r.y = f2bf(o1);
  *(ushort2*)&o[tid * 2] = r;
}

// gx2T[g2][m][*] = t_saT[(m&3)*8+(g2&7)][(g2>>3)*256+(m>>2)][*]. grid 32768
__global__ __launch_bounds__(256) void gather_x2(
    const u16* __restrict__ T, u16* __restrict__ X2)
{
  int bid = blockIdx.x;
  int g2 = bid >> 10, m = bid & 1023;
  long src = ((long)((m & 3) * 8 + (g2 & 7)) * 1024 + (g2 >> 3) * 256 + (m >> 2)) * 512;
  long dst = ((long)g2 * 1024 + m) * 512;
  int t2 = threadIdx.x * 2;
  *(ushort2*)&X2[dst + t2] = *(const ushort2*)&T[src + t2];
}

// ybar = mean over 24 planes (bf16 in, fp32 out). grid 2048
__global__ __launch_bounds__(256) void ybar_k(
    const u16* __restrict__ Y, float* __restrict__ yb)
{
  long idx = (long)blockIdx.x * 256 + threadIdx.x;
  float s = 0.f;
#pragma unroll
  for (int g = 0; g < 24; ++g) s += bf2f(Y[(long)g * kPLANE + idx]);
  yb[idx] = s * (1.f / 24.f);
}

// h_first[b][n][c] = gx2T[b][n][c] + ybar[n][c]*phiF[b][n][c]. grid 16384
__global__ __launch_bounds__(256) void hfirst_k(
    const u16* __restrict__ gx2, const u16* __restrict__ phiF,
    const float* __restrict__ yb, u16* __restrict__ h)
{
  long idx = (long)blockIdx.x * 256 + threadIdx.x;
  long p = idx & (kPLANE - 1);
  h[idx] = f2bf(bf2f(gx2[idx]) + yb[p] * bf2f(phiF[idx]));
}

// out[b][c][gp2*1024+m] = (gp2==0 ? crossT[b] : gx2T[g2])[m][c]. grid(32,16,32) block(32,8)
__global__ __launch_bounds__(256) void assemble_t(
    const u16* __restrict__ gx2T, const u16* __restrict__ crossT,
    float* __restrict__ out)
{
  int g2 = blockIdx.z, gp2 = g2 >> 3, b = g2 & 7;
  const u16* S = (gp2 == 0) ? crossT + (long)b * kPLANE : gx2T + (long)g2 * kPLANE;
  __shared__ u16 t[32][33];
  int m0 = blockIdx.x * 32, c0 = blockIdx.y * 32;
  int tx = threadIdx.x, ty = threadIdx.y;
  for (int r = ty; r < 32; r += 8) t[r][tx] = S[(long)(m0 + r) * 512 + c0 + tx];
  __syncthreads();
  for (int r = ty; r < 32; r += 8)
    out[((long)b * 512 + c0 + r) * 4096 + gp2 * 1024 + m0 + tx] = bf2f(t[tx][r]);
}

extern "C" void kernel_launch(void* const* d_in, const int* in_sizes, int n_in,
                              void* d_out, int out_size, void* d_ws, size_t ws_size,
                              hipStream_t stream)
{
  const float* feat = (const float*)d_in[0];
  const float* tg1 = (const float*)d_in[4];  const float* tb1 = (const float*)d_in[5];
  const float* tf1b = (const float*)d_in[7];
  const float* tf2b = (const float*)d_in[9];
  const float* tg2 = (const float*)d_in[10]; const float* tb2 = (const float*)d_in[11];
  const float* cg1 = (const float*)d_in[16]; const float* cb1 = (const float*)d_in[17];
  const float* cf1b = (const float*)d_in[19];
  const float* cf2b = (const float*)d_in[21];
  const float* cg2 = (const float*)d_in[22]; const float* cb2 = (const float*)d_in[23];

  // ---- ws layout (peak 112 MiB) ----
  char* wsb = (char*)d_ws;
  u16* WP = (u16*)wsb;                 // 7 proj weights (d,c) bf16: 3.5 MiB
  u16* WF = (u16*)(wsb + 4 * MB);      // 4 FFN weights bf16: 8 MiB
  float* SM = (float*)(wsb + 12 * MB); // fp32 smalls
  float* QG = SM;                      // 32*512
  float* SC = SM + 16384;              // 32*1024
  float* AL = SM + 49152;              // 32*1024
  float* KS = SM + 81920;              // 32*512
  float* Zb = SM + 98304;              // 32*1024
  float* ZR = SM + 131072;             // 24*1024
  float* YB = SM + 155648;             // 1024*512 fp32
  u16* P2 = (u16*)(wsb + 16 * MB);     // 32 planes
  u16* P3 = (u16*)(wsb + 48 * MB);     // 32 planes
  u16* P4 = (u16*)(wsb + 80 * MB);     // 32 planes (ends 112 MiB)

  // ---- d_out (64 MiB) doubles as scratch until final assemble ----
  char* ob = (char*)d_out;
  u16* KV  = (u16*)ob;                 // SA kvT: 16 MiB
  u16* GXT = (u16*)(ob + 16 * MB);     // gxT: 32 MiB (dead after y GEMM)
  u16* HID = (u16*)ob;                 // FFN hidden chunk: 32 MiB (kv dead)
  u16* KV2 = (u16*)(ob + 32 * MB);     // cross kvT: 4 MiB
  u16* PHF = (u16*)(ob + 36 * MB);     // phi_first: 8 MiB
  u16* K0S = (u16*)(ob + 44 * MB);     // k0*alpha (c,n): 8 MiB
  u16* V0S = (u16*)(ob + 52 * MB);     // v0 (c,n): 8 MiB

  u16 *WPqk = WP,           *WPv  = WP + SZW,     *WPphi = WP + 2 * SZW,
      *WPcq = WP + 3 * SZW, *WPck = WP + 4 * SZW, *WPcv  = WP + 5 * SZW,
      *WPcphi = WP + 6 * SZW;
  u16 *WF1 = WF, *WF2 = WF + 1048576, *WF3 = WF + 2097152, *WF4 = WF + 3145728;

  dim3 b256(256), bT(32, 8);
  const float rsc = 1.0f / sqrtf(512.0f);
  const long PL = kPLANE;

  // 0. weight casts (no transposes needed in NT world)
  const float* wsrc[7] = {(const float*)d_in[1], (const float*)d_in[2], (const float*)d_in[3],
                          (const float*)d_in[12], (const float*)d_in[13], (const float*)d_in[14],
                          (const float*)d_in[15]};
  for (int i = 0; i < 7; ++i)
    castf2b<<<1024, b256, 0, stream>>>(wsrc[i], WP + i * SZW, 262144);
  castf2b<<<4096, b256, 0, stream>>>((const float*)d_in[6],  WF1, 1048576);
  castf2b<<<4096, b256, 0, stream>>>((const float*)d_in[8],  WF2, 1048576);
  castf2b<<<4096, b256, 0, stream>>>((const float*)d_in[18], WF3, 1048576);
  castf2b<<<4096, b256, 0, stream>>>((const float*)d_in[20], WF4, 1048576);

  // ---------------- SA block (all tensors (g,n,c) T-layout) ----------------
  gather_feat<<<dim3(32, 16, 8), bT, 0, stream>>>(feat, GXT);
  // qT = phi(gxT . Wqk^T)
  gemm_mfma<<<dim3(4, 8, 32), b256, 0, stream>>>(GXT, PL, 31, WPqk, 0, 0, P2, PL,
      1024, 512, 512, 1.f, 2, nullptr, nullptr, 0, nullptr, nullptr);
  colsum<<<dim3(2, 32), b256, 0, stream>>>(P2, PL, nullptr, QG, 1.f / 1024.f);
  rowdot<<<dim3(256, 32), b256, 0, stream>>>(P2, PL, QG, 31, SC, 0);
  softmax_row<<<32, b256, 0, stream>>>(SC, AL);
  // vT, then transpose v and k'=q*alpha into (c,n) layout for kv GEMM
  gemm_mfma<<<dim3(4, 8, 32), b256, 0, stream>>>(GXT, PL, 31, WPv, 0, 0, P3, PL,
      1024, 512, 512, 1.f, 0, nullptr, nullptr, 0, nullptr, nullptr);
  transpose_b<<<dim3(32, 16, 32), bT, 0, stream>>>(P3, P4, nullptr);  // v
  transpose_b<<<dim3(32, 16, 32), bT, 0, stream>>>(P2, P3, AL);       // k'
  // kvT[d][c] = sum_n v[d][n] k'[c][n] * rsc
  gemm_mfma<<<dim3(4, 4, 32), b256, 0, stream>>>(P4, PL, 31, P3, PL, 31, KV, SZW,
      512, 512, 1024, rsc, 0, nullptr, nullptr, 0, nullptr, nullptr);
  colsum<<<dim3(2, 32), b256, 0, stream>>>(P2, PL, AL, KS, 1.f);
  rowdot<<<dim3(256, 32), b256, 0, stream>>>(P2, PL, KS, 31, Zb, 1);
  // phixT
  gemm_mfma<<<dim3(4, 8, 32), b256, 0, stream>>>(GXT, PL, 31, WPphi, 0, 0, P4, PL,
      1024, 512, 512, 1.f, 0, nullptr, nullptr, 0, nullptr, nullptr);
  // h_preT = qT.kvT * z[n] * phixT + gxT
  gemm_mfma<<<dim3(4, 8, 32), b256, 0, stream>>>(P2, PL, 31, KV, SZW, 31, P3, PL,
      1024, 512, 512, 1.f, 0, nullptr, Zb, 1024, P4, GXT);
  ln_rows<<<32768, b256, 0, stream>>>(P3, tg1, tb1, P2, 0);
  // FFN 512->2048->512, 4 chunks of 8192 rows
  for (int ch = 0; ch < 4; ++ch) {
    const u16* Hc = P2 + (long)ch * 8 * PL;
    gemm_mfma<<<dim3(16, 64, 1), b256, 0, stream>>>(Hc, 0, 0, WF1, 0, 0, HID, 0,
        8192, 2048, 512, 1.f, 1, tf1b, nullptr, 0, nullptr, nullptr);
    gemm_mfma<<<dim3(4, 64, 1), b256, 0, stream>>>(HID, 0, 0, WF2, 0, 0,
        P3 + (long)ch * 8 * PL, 0, 8192, 512, 2048, 1.f, 0, tf2b, nullptr, 0, nullptr, Hc);
  }
  ln_rows<<<32768, b256, 0, stream>>>(P3, tg2, tb2, P2, 1);       // t_saT
  gather_x2<<<32768, b256, 0, stream>>>(P2, P4);                  // gx2T

  // ---------------- cross block ----------------
  gemm_mfma<<<dim3(4, 8, 24), b256, 0, stream>>>(P4 + 8 * PL, PL, 31, WPcq, 0, 0, P2, PL,
      1024, 512, 512, 1.f, 2, nullptr, nullptr, 0, nullptr, nullptr);        // q_restT
  gemm_mfma<<<dim3(4, 8, 24), b256, 0, stream>>>(P4 + 8 * PL, PL, 31, WPcphi, 0, 0, P3, PL,
      1024, 512, 512, 1.f, 0, nullptr, nullptr, 0, nullptr, nullptr);        // phi_restT
  gemm_mfma<<<dim3(4, 8, 8), b256, 0, stream>>>(P4, PL, 31, WPck, 0, 0, P2 + 24 * PL, PL,
      1024, 512, 512, 1.f, 2, nullptr, nullptr, 0, nullptr, nullptr);        // k0T
  gemm_mfma<<<dim3(4, 8, 8), b256, 0, stream>>>(P4, PL, 31, WPcv, 0, 0, P3 + 24 * PL, PL,
      1024, 512, 512, 1.f, 0, nullptr, nullptr, 0, nullptr, nullptr);        // v0T
  gemm_mfma<<<dim3(4, 8, 8), b256, 0, stream>>>(P4, PL, 31, WPcphi, 0, 0, PHF, PL,
      1024, 512, 512, 1.f, 0, nullptr, nullptr, 0, nullptr, nullptr);        // phi_firstT
  colsum<<<dim3(2, 8), b256, 0, stream>>>(P2 + 24 * PL, PL, nullptr, QG, 1.f / 1024.f);
  rowdot<<<dim3(256, 8), b256, 0, stream>>>(P2 + 24 * PL, PL, QG, 7, SC, 0);
  softmax_row<<<8, b256, 0, stream>>>(SC, AL);
  transpose_b<<<dim3(32, 16, 8), bT, 0, stream>>>(P2 + 24 * PL, K0S, AL);  // k0'
  transpose_b<<<dim3(32, 16, 8), bT, 0, stream>>>(P3 + 24 * PL, V0S, nullptr);
  gemm_mfma<<<dim3(4, 4, 8), b256, 0, stream>>>(V0S, PL, 31, K0S, PL, 31, KV2, SZW,
      512, 512, 1024, rsc, 0, nullptr, nullptr, 0, nullptr, nullptr);
  colsum<<<dim3(2, 8), b256, 0, stream>>>(P2 + 24 * PL, PL, AL, KS, 1.f);
  rowdot<<<dim3(256, 24), b256, 0, stream>>>(P2, PL, KS, 7, ZR, 1);
  // y_restT = q_restT.kvT2[g&7] * z[n] * phi_restT  (in-place into P3)
  gemm_mfma<<<dim3(4, 8, 24), b256, 0, stream>>>(P2, PL, 31, KV2, SZW, 7, P3, PL,
      1024, 512, 512, 1.f, 0, nullptr, ZR, 1024, P3, nullptr);
  ybar_k<<<2048, b256, 0, stream>>>(P3, YB);
  hfirst_k<<<16384, b256, 0, stream>>>(P4, PHF, YB, P2 + 24 * PL);   // h_first
  ln_rows<<<8192, b256, 0, stream>>>(P2 + 24 * PL, cg1, cb1, P3 + 24 * PL, 0);
  gemm_mfma<<<dim3(16, 64, 1), b256, 0, stream>>>(P3 + 24 * PL, 0, 0, WF3, 0, 0, HID, 0,
      8192, 2048, 512, 1.f, 1, cf1b, nullptr, 0, nullptr, nullptr);
  gemm_mfma<<<dim3(4, 64, 1), b256, 0, stream>>>(HID, 0, 0, WF4, 0, 0, P2 + 24 * PL, 0,
      8192, 512, 2048, 1.f, 0, cf2b, nullptr, 0, nullptr, P3 + 24 * PL);
  ln_rows<<<8192, b256, 0, stream>>>(P2 + 24 * PL, cg2, cb2, P3 + 24 * PL, 1); // crossT
  assemble_t<<<dim3(32, 16, 32), bT, 0, stream>>>(P4, P3 + 24 * PL, (float*)d_out);
}

// Round 7
// 1285.321 us; speedup vs baseline: 4.0096x; 1.3919x over previous
//
#include <hip/hip_runtime.h>
#include <math.h>

using u16 = unsigned short;
typedef __attribute__((ext_vector_type(8))) short short8;
typedef __attribute__((ext_vector_type(4))) float f32x4;

// B=8, C=512, N=4096, GP=4 -> G=32 groups, NG=1024, F=2048
constexpr long kPLANE = 1024l * 512;     // elems per (g) plane, T-layout (n, c)
constexpr long SZW    = 512l * 512;
constexpr long MB     = 1l << 20;

__device__ __forceinline__ float bf2f(u16 u) {
  return __uint_as_float(((unsigned int)u) << 16);
}
__device__ __forceinline__ u16 f2bf(float f) {
  unsigned int x = __float_as_uint(f);
  x += 0x7fffu + ((x >> 16) & 1u);
  return (u16)(x >> 16);
}

// ---------------------------------------------------------------------------
// Unified MFMA GEMM (NT form): Out[g][m][n] = epi( scale * sum_k A[m][k]*B[n][k] )
// A (M x K) bf16 K-contig, B (N x K) bf16 K-contig. 128x128 tile, BK=32,
// 4 waves each 64x64 via 4x4 v_mfma_f32_16x16x32_bf16.
// Register-prefetch double-buffered LDS staging (one barrier per K-step).
// Operands swapped in mfma so each lane holds 4 consecutive n at fixed m ->
// ushort4 epilogue stores.
// epi: *rowscale[g][m] -> *pmul[g][m][n] -> +bias[n] -> +resid[g][m][n] -> act
// act: 0 none, 1 relu, 2 relu+1 (phi). pmul may alias Out.
// ---------------------------------------------------------------------------
__global__ __launch_bounds__(256) void gemm_mfma(
    const u16* __restrict__ A, long sA, int amask,
    const u16* __restrict__ B, long sB, int bmask,
    u16* __restrict__ Out, long sO,
    int M, int Nn, int K, float scale, int act,
    const float* __restrict__ bias,
    const float* __restrict__ rowscale, long sRS,
    const u16* __restrict__ pmul, const u16* __restrict__ resid)
{
  int g = blockIdx.z;
  const u16* Ag = A + (long)(g & amask) * sA;
  const u16* Bg = B + (long)(g & bmask) * sB;
  u16* Og = Out + (long)g * sO;
  int m0 = blockIdx.y * 128, n0 = blockIdx.x * 128;

  __shared__ __align__(16) u16 As[2][128 * 32];
  __shared__ __align__(16) u16 Bs[2][128 * 32];

  int tid = threadIdx.x;
  int w = tid >> 6, L = tid & 63;
  int wm = (w >> 1) * 64, wn = (w & 1) * 64;
  int l15 = L & 15, l4 = L >> 4;

  f32x4 acc[4][4] = {};

  // staging: 512 16B-chunks per 128x32 tile; thread covers chunks tid, tid+256
  int r0 = tid >> 2, r1 = r0 + 64;
  int kk = (tid & 3) * 8;
  int s0 = r0 * 32 + kk, s1 = r1 * 32 + kk;
  const u16* gA0 = Ag + (long)(m0 + r0) * K + kk;
  const u16* gA1 = Ag + (long)(m0 + r1) * K + kk;
  const u16* gB0 = Bg + (long)(n0 + r0) * K + kk;
  const u16* gB1 = Bg + (long)(n0 + r1) * K + kk;

  // preload tile 0 into LDS buffer 0
  short8 ra0 = *(const short8*)gA0;
  short8 ra1 = *(const short8*)gA1;
  short8 rb0 = *(const short8*)gB0;
  short8 rb1 = *(const short8*)gB1;
  *(short8*)&As[0][s0] = ra0; *(short8*)&As[0][s1] = ra1;
  *(short8*)&Bs[0][s0] = rb0; *(short8*)&Bs[0][s1] = rb1;
  __syncthreads();

  int nsteps = K >> 5;
  for (int ks = 0; ks < nsteps; ++ks) {
    int cur = ks & 1;
    if (ks + 1 < nsteps) {             // prefetch next K-tile into registers
      int ko = (ks + 1) << 5;
      ra0 = *(const short8*)(gA0 + ko);
      ra1 = *(const short8*)(gA1 + ko);
      rb0 = *(const short8*)(gB0 + ko);
      rb1 = *(const short8*)(gB1 + ko);
    }
    short8 af[4], bf[4];
#pragma unroll
    for (int mi = 0; mi < 4; ++mi)
      af[mi] = *(const short8*)&As[cur][(wm + mi * 16 + l15) * 32 + l4 * 8];
#pragma unroll
    for (int ni = 0; ni < 4; ++ni)
      bf[ni] = *(const short8*)&Bs[cur][(wn + ni * 16 + l15) * 32 + l4 * 8];
#pragma unroll
    for (int mi = 0; mi < 4; ++mi)
#pragma unroll
      for (int ni = 0; ni < 4; ++ni)
        acc[mi][ni] = __builtin_amdgcn_mfma_f32_16x16x32_bf16(bf[ni], af[mi], acc[mi][ni], 0, 0, 0);
    if (ks + 1 < nsteps) {             // write prefetched tile to other buffer
      int nxt = cur ^ 1;
      *(short8*)&As[nxt][s0] = ra0; *(short8*)&As[nxt][s1] = ra1;
      *(short8*)&Bs[nxt][s0] = rb0; *(short8*)&Bs[nxt][s1] = rb1;
    }
    __syncthreads();
  }

  // epilogue (operand-swapped D): lane holds n = nb..nb+3 at fixed m
  //   m = m0+wm+mi*16+l15 ; nb = n0+wn+ni*16+l4*4
#pragma unroll
  for (int mi = 0; mi < 4; ++mi) {
    int m = m0 + wm + mi * 16 + l15;
    float rs = rowscale ? rowscale[(long)g * sRS + m] : 1.f;
    float srs = scale * rs;
#pragma unroll
    for (int ni = 0; ni < 4; ++ni) {
      int nb = n0 + wn + ni * 16 + l4 * 4;
      long off = (long)m * Nn + nb;
      float v[4];
#pragma unroll
      for (int r = 0; r < 4; ++r) v[r] = acc[mi][ni][r] * srs;
      if (pmul) {
        ushort4 pm = *(const ushort4*)&pmul[(long)g * sO + off];
        v[0] *= bf2f(pm.x); v[1] *= bf2f(pm.y); v[2] *= bf2f(pm.z); v[3] *= bf2f(pm.w);
      }
      if (bias) {
        float4 bi = *(const float4*)&bias[nb];
        v[0] += bi.x; v[1] += bi.y; v[2] += bi.z; v[3] += bi.w;
      }
      if (resid) {
        ushort4 rd = *(const ushort4*)&resid[(long)g * sO + off];
        v[0] += bf2f(rd.x); v[1] += bf2f(rd.y); v[2] += bf2f(rd.z); v[3] += bf2f(rd.w);
      }
      if (act == 1) {
#pragma unroll
        for (int r = 0; r < 4; ++r) v[r] = fmaxf(v[r], 0.f);
      } else if (act == 2) {
#pragma unroll
        for (int r = 0; r < 4; ++r) v[r] = fmaxf(v[r], 0.f) + 1.f;
      }
      ushort4 o; o.x = f2bf(v[0]); o.y = f2bf(v[1]); o.z = f2bf(v[2]); o.w = f2bf(v[3]);
      *(ushort4*)&Og[off] = o;
    }
  }
}

// fp32 -> bf16 flat cast
__global__ __launch_bounds__(256) void castf2b(
    const float* __restrict__ src, u16* __restrict__ dst, int n)
{
  int i = blockIdx.x * 256 + threadIdx.x;
  if (i < n) dst[i] = f2bf(src[i]);
}

// gxT[gp*8+b][n][c] = feat[b][c][4n+gp]  (fp32 -> bf16). grid(32,16,8) block(32,8)
__global__ __launch_bounds__(256) void gather_feat(
    const float* __restrict__ feat, u16* __restrict__ gxT)
{
  __shared__ float t[32][132];
  int b = blockIdx.z, c0 = blockIdx.y * 32, nf0 = blockIdx.x * 128;
  int tx = threadIdx.x, ty = threadIdx.y;
  for (int r = ty; r < 32; r += 8)
    *(float4*)&t[r][tx * 4] = *(const float4*)&feat[((long)b * 512 + c0 + r) * 4096 + nf0 + tx * 4];
  __syncthreads();
  int n0o = nf0 >> 2;
  for (int gp = 0; gp < 4; ++gp) {
    long gbase = (long)(gp * 8 + b) * kPLANE;
    for (int jr = ty; jr < 32; jr += 8)
      gxT[gbase + (long)(n0o + jr) * 512 + c0 + tx] = f2bf(t[tx][jr * 4 + gp]);
  }
}

// out[g][c][n] = in[g][n][c] * (alpha ? alpha[g][n] : 1). grid(32,16,G) block(32,8)
__global__ __launch_bounds__(256) void transpose_b(
    const u16* __restrict__ in, u16* __restrict__ out, const float* __restrict__ alpha)
{
  int g = blockIdx.z;
  const u16* I = in + (long)g * kPLANE;
  u16* O = out + (long)g * kPLANE;
  __shared__ u16 t[32][33];
  int n0 = blockIdx.x * 32, c0 = blockIdx.y * 32;
  int tx = threadIdx.x, ty = threadIdx.y;
  for (int r = ty; r < 32; r += 8) t[r][tx] = I[(long)(n0 + r) * 512 + c0 + tx];
  __syncthreads();
  float al = alpha ? alpha[(long)g * 1024 + n0 + tx] : 1.f;
  for (int r = ty; r < 32; r += 8)
    O[(long)(c0 + r) * 1024 + n0 + tx] = f2bf(bf2f(t[tx][r]) * al);
}

// out[g][c] = scale * sum_n X[g][n][c] * (alpha ? alpha[g][n] : 1). grid(2,G)
__global__ __launch_bounds__(256) void colsum(
    const u16* __restrict__ X, long sX, const float* __restrict__ alpha,
    float* __restrict__ out, float scale)
{
  int g = blockIdx.y;
  int c = blockIdx.x * 256 + threadIdx.x;
  const u16* Xg = X + (long)g * sX;
  float s = 0.f;
  for (int n = 0; n < 1024; ++n)
    s += bf2f(Xg[(long)n * 512 + c]) * (alpha ? alpha[(long)g * 1024 + n] : 1.f);
  out[(long)g * 512 + c] = s * scale;
}

// out[g][n] = f( sum_c X[g][n][c] * w[(g&wmask)][c] ). mode1: 1/(x+1e-6). grid(256,G)
__global__ __launch_bounds__(256) void rowdot(
    const u16* __restrict__ X, long sX, const float* __restrict__ w, int wmask,
    float* __restrict__ out, int mode)
{
  int g = blockIdx.y;
  int n = blockIdx.x * 4 + (threadIdx.x >> 6);
  int L = threadIdx.x & 63;
  const u16* row = X + (long)g * sX + (long)n * 512;
  short8 xv = *(const short8*)&row[L * 8];
  const float* wg = w + (long)(g & wmask) * 512;
  float4 w0 = *(const float4*)&wg[L * 8];
  float4 w1 = *(const float4*)&wg[L * 8 + 4];
  float s = bf2f((u16)xv[0]) * w0.x + bf2f((u16)xv[1]) * w0.y +
            bf2f((u16)xv[2]) * w0.z + bf2f((u16)xv[3]) * w0.w +
            bf2f((u16)xv[4]) * w1.x + bf2f((u16)xv[5]) * w1.y +
            bf2f((u16)xv[6]) * w1.z + bf2f((u16)xv[7]) * w1.w;
#pragma unroll
  for (int off = 32; off >= 1; off >>= 1) s += __shfl_down(s, off);
  if (L == 0) out[(long)g * 1024 + n] = mode ? 1.f / (s + 1e-6f) : s;
}

// alpha[g][n] = softmax_n(sc[g])[n] * 1024. grid(G)
__global__ __launch_bounds__(256) void softmax_row(
    const float* __restrict__ sc, float* __restrict__ out)
{
  int g = blockIdx.x, tid = threadIdx.x;
  const float* s = sc + (long)g * 1024;
  float* o = out + (long)g * 1024;
  __shared__ float red[256];
  float lm = -3.4e38f;
  for (int n = tid; n < 1024; n += 256) lm = fmaxf(lm, s[n]);
  red[tid] = lm; __syncthreads();
  for (int st = 128; st; st >>= 1) { if (tid < st) red[tid] = fmaxf(red[tid], red[tid + st]); __syncthreads(); }
  float mx = red[0]; __syncthreads();
  float ls = 0.f;
  for (int n = tid; n < 1024; n += 256) ls += __expf(s[n] - mx);
  red[tid] = ls; __syncthreads();
  for (int st = 128; st; st >>= 1) { if (tid < st) red[tid] += red[tid + st]; __syncthreads(); }
  float inv = 1024.f / red[0];
  for (int n = tid; n < 1024; n += 256) o[n] = __expf(s[n] - mx) * inv;
}

// LayerNorm over 512-wide contiguous rows, bf16 in/out, fp32 gamma/beta.
__global__ __launch_bounds__(256) void ln_rows(
    const u16* __restrict__ X, const float* __restrict__ gamma,
    const float* __restrict__ beta, u16* __restrict__ Out, int relu)
{
  long m = blockIdx.x;
  const u16* x = X + m * 512;
  u16* o = Out + m * 512;
  int tid = threadIdx.x;
  ushort2 u2 = *(const ushort2*)&x[tid * 2];
  float v0 = bf2f(u2.x), v1 = bf2f(u2.y);
  __shared__ float red[256];
  red[tid] = v0 + v1; __syncthreads();
  for (int st = 128; st; st >>= 1) { if (tid < st) red[tid] += red[tid + st]; __syncthreads(); }
  float mu = red[0] * (1.f / 512.f);
  __syncthreads();
  float d0 = v0 - mu, d1 = v1 - mu;
  red[tid] = d0 * d0 + d1 * d1; __syncthreads();
  for (int st = 128; st; st >>= 1) { if (tid < st) red[tid] += red[tid + st]; __syncthreads(); }
  float rs = rsqrtf(red[0] * (1.f / 512.f) + 1e-6f);
  float2 gm = *(const float2*)&gamma[tid * 2];
  float2 bt = *(const float2*)&beta[tid * 2];
  float o0 = d0 * rs * gm.x + bt.x, o1 = d1 * rs * gm.y + bt.y;
  if (relu) { o0 = fmaxf(o0, 0.f); o1 = fmaxf(o1, 0.f); }
  ushort2 r; r.x = f2bf(o0); r.y = f2bf(o1);
  *(ushort2*)&o[tid * 2] = r;
}

// gx2T[g2][m][*] = t_saT[(m&3)*8+(g2&7)][(g2>>3)*256+(m>>2)][*]. grid 32768
__global__ __launch_bounds__(256) void gather_x2(
    const u16* __restrict__ T, u16* __restrict__ X2)
{
  int bid = blockIdx.x;
  int g2 = bid >> 10, m = bid & 1023;
  long src = ((long)((m & 3) * 8 + (g2 & 7)) * 1024 + (g2 >> 3) * 256 + (m >> 2)) * 512;
  long dst = ((long)g2 * 1024 + m) * 512;
  int t2 = threadIdx.x * 2;
  *(ushort2*)&X2[dst + t2] = *(const ushort2*)&T[src + t2];
}

// ybar = mean over 24 planes (bf16 in, fp32 out). grid 2048
__global__ __launch_bounds__(256) void ybar_k(
    const u16* __restrict__ Y, float* __restrict__ yb)
{
  long idx = (long)blockIdx.x * 256 + threadIdx.x;
  float s = 0.f;
#pragma unroll
  for (int g = 0; g < 24; ++g) s += bf2f(Y[(long)g * kPLANE + idx]);
  yb[idx] = s * (1.f / 24.f);
}

// h_first[b][n][c] = gx2T[b][n][c] + ybar[n][c]*phiF[b][n][c]. grid 16384
__global__ __launch_bounds__(256) void hfirst_k(
    const u16* __restrict__ gx2, const u16* __restrict__ phiF,
    const float* __restrict__ yb, u16* __restrict__ h)
{
  long idx = (long)blockIdx.x * 256 + threadIdx.x;
  long p = idx & (kPLANE - 1);
  h[idx] = f2bf(bf2f(gx2[idx]) + yb[p] * bf2f(phiF[idx]));
}

// out[b][c][gp2*1024+m] = (gp2==0 ? crossT[b] : gx2T[g2])[m][c]. grid(32,16,32) block(32,8)
__global__ __launch_bounds__(256) void assemble_t(
    const u16* __restrict__ gx2T, const u16* __restrict__ crossT,
    float* __restrict__ out)
{
  int g2 = blockIdx.z, gp2 = g2 >> 3, b = g2 & 7;
  const u16* S = (gp2 == 0) ? crossT + (long)b * kPLANE : gx2T + (long)g2 * kPLANE;
  __shared__ u16 t[32][33];
  int m0 = blockIdx.x * 32, c0 = blockIdx.y * 32;
  int tx = threadIdx.x, ty = threadIdx.y;
  for (int r = ty; r < 32; r += 8) t[r][tx] = S[(long)(m0 + r) * 512 + c0 + tx];
  __syncthreads();
  for (int r = ty; r < 32; r += 8)
    out[((long)b * 512 + c0 + r) * 4096 + gp2 * 1024 + m0 + tx] = bf2f(t[tx][r]);
}

extern "C" void kernel_launch(void* const* d_in, const int* in_sizes, int n_in,
                              void* d_out, int out_size, void* d_ws, size_t ws_size,
                              hipStream_t stream)
{
  const float* feat = (const float*)d_in[0];
  const float* tg1 = (const float*)d_in[4];  const float* tb1 = (const float*)d_in[5];
  const float* tf1b = (const float*)d_in[7];
  const float* tf2b = (const float*)d_in[9];
  const float* tg2 = (const float*)d_in[10]; const float* tb2 = (const float*)d_in[11];
  const float* cg1 = (const float*)d_in[16]; const float* cb1 = (const float*)d_in[17];
  const float* cf1b = (const float*)d_in[19];
  const float* cf2b = (const float*)d_in[21];
  const float* cg2 = (const float*)d_in[22]; const float* cb2 = (const float*)d_in[23];

  // ---- ws layout (peak 112 MiB) ----
  char* wsb = (char*)d_ws;
  u16* WP = (u16*)wsb;                 // 7 proj weights (d,c) bf16: 3.5 MiB
  u16* WF = (u16*)(wsb + 4 * MB);      // 4 FFN weights bf16: 8 MiB
  float* SM = (float*)(wsb + 12 * MB); // fp32 smalls
  float* QG = SM;                      // 32*512
  float* SC = SM + 16384;              // 32*1024
  float* AL = SM + 49152;              // 32*1024
  float* KS = SM + 81920;              // 32*512
  float* Zb = SM + 98304;              // 32*1024
  float* ZR = SM + 131072;             // 24*1024
  float* YB = SM + 155648;             // 1024*512 fp32
  u16* P2 = (u16*)(wsb + 16 * MB);     // 32 planes
  u16* P3 = (u16*)(wsb + 48 * MB);     // 32 planes
  u16* P4 = (u16*)(wsb + 80 * MB);     // 32 planes (ends 112 MiB)

  // ---- d_out (64 MiB) doubles as scratch until final assemble ----
  char* ob = (char*)d_out;
  u16* KV  = (u16*)ob;                 // SA kvT: 16 MiB
  u16* GXT = (u16*)(ob + 16 * MB);     // gxT: 32 MiB (dead after y GEMM)
  u16* HID = (u16*)ob;                 // FFN hidden chunk: 64 MiB (kv+gxT dead)
  u16* KV2 = (u16*)(ob + 32 * MB);     // cross kvT: 4 MiB
  u16* PHF = (u16*)(ob + 36 * MB);     // phi_first: 8 MiB
  u16* K0S = (u16*)(ob + 44 * MB);     // k0*alpha (c,n): 8 MiB
  u16* V0S = (u16*)(ob + 52 * MB);     // v0 (c,n): 8 MiB

  u16 *WPqk = WP,           *WPv  = WP + SZW,     *WPphi = WP + 2 * SZW,
      *WPcq = WP + 3 * SZW, *WPck = WP + 4 * SZW, *WPcv  = WP + 5 * SZW,
      *WPcphi = WP + 6 * SZW;
  u16 *WF1 = WF, *WF2 = WF + 1048576, *WF3 = WF + 2097152, *WF4 = WF + 3145728;

  dim3 b256(256), bT(32, 8);
  const float rsc = 1.0f / sqrtf(512.0f);
  const long PL = kPLANE;

  // 0. weight casts (no transposes needed in NT world)
  const float* wsrc[7] = {(const float*)d_in[1], (const float*)d_in[2], (const float*)d_in[3],
                          (const float*)d_in[12], (const float*)d_in[13], (const float*)d_in[14],
                          (const float*)d_in[15]};
  for (int i = 0; i < 7; ++i)
    castf2b<<<1024, b256, 0, stream>>>(wsrc[i], WP + i * SZW, 262144);
  castf2b<<<4096, b256, 0, stream>>>((const float*)d_in[6],  WF1, 1048576);
  castf2b<<<4096, b256, 0, stream>>>((const float*)d_in[8],  WF2, 1048576);
  castf2b<<<4096, b256, 0, stream>>>((const float*)d_in[18], WF3, 1048576);
  castf2b<<<4096, b256, 0, stream>>>((const float*)d_in[20], WF4, 1048576);

  // ---------------- SA block (all tensors (g,n,c) T-layout) ----------------
  gather_feat<<<dim3(32, 16, 8), bT, 0, stream>>>(feat, GXT);
  // qT = phi(gxT . Wqk^T)
  gemm_mfma<<<dim3(4, 8, 32), b256, 0, stream>>>(GXT, PL, 31, WPqk, 0, 0, P2, PL,
      1024, 512, 512, 1.f, 2, nullptr, nullptr, 0, nullptr, nullptr);
  colsum<<<dim3(2, 32), b256, 0, stream>>>(P2, PL, nullptr, QG, 1.f / 1024.f);
  rowdot<<<dim3(256, 32), b256, 0, stream>>>(P2, PL, QG, 31, SC, 0);
  softmax_row<<<32, b256, 0, stream>>>(SC, AL);
  // vT, then transpose v and k'=q*alpha into (c,n) layout for kv GEMM
  gemm_mfma<<<dim3(4, 8, 32), b256, 0, stream>>>(GXT, PL, 31, WPv, 0, 0, P3, PL,
      1024, 512, 512, 1.f, 0, nullptr, nullptr, 0, nullptr, nullptr);
  transpose_b<<<dim3(32, 16, 32), bT, 0, stream>>>(P3, P4, nullptr);  // v
  transpose_b<<<dim3(32, 16, 32), bT, 0, stream>>>(P2, P3, AL);       // k'
  // kvT[d][c] = sum_n v[d][n] k'[c][n] * rsc
  gemm_mfma<<<dim3(4, 4, 32), b256, 0, stream>>>(P4, PL, 31, P3, PL, 31, KV, SZW,
      512, 512, 1024, rsc, 0, nullptr, nullptr, 0, nullptr, nullptr);
  colsum<<<dim3(2, 32), b256, 0, stream>>>(P2, PL, AL, KS, 1.f);
  rowdot<<<dim3(256, 32), b256, 0, stream>>>(P2, PL, KS, 31, Zb, 1);
  // phixT
  gemm_mfma<<<dim3(4, 8, 32), b256, 0, stream>>>(GXT, PL, 31, WPphi, 0, 0, P4, PL,
      1024, 512, 512, 1.f, 0, nullptr, nullptr, 0, nullptr, nullptr);
  // h_preT = qT.kvT * z[n] * phixT + gxT
  gemm_mfma<<<dim3(4, 8, 32), b256, 0, stream>>>(P2, PL, 31, KV, SZW, 31, P3, PL,
      1024, 512, 512, 1.f, 0, nullptr, Zb, 1024, P4, GXT);
  ln_rows<<<32768, b256, 0, stream>>>(P3, tg1, tb1, P2, 0);
  // FFN 512->2048->512, 2 chunks of 16384 rows (HID = full 64 MiB d_out)
  for (int ch = 0; ch < 2; ++ch) {
    const u16* Hc = P2 + (long)ch * 16 * PL;
    gemm_mfma<<<dim3(16, 128, 1), b256, 0, stream>>>(Hc, 0, 0, WF1, 0, 0, HID, 0,
        16384, 2048, 512, 1.f, 1, tf1b, nullptr, 0, nullptr, nullptr);
    gemm_mfma<<<dim3(4, 128, 1), b256, 0, stream>>>(HID, 0, 0, WF2, 0, 0,
        P3 + (long)ch * 16 * PL, 0, 16384, 512, 2048, 1.f, 0, tf2b, nullptr, 0, nullptr, Hc);
  }
  ln_rows<<<32768, b256, 0, stream>>>(P3, tg2, tb2, P2, 1);       // t_saT
  gather_x2<<<32768, b256, 0, stream>>>(P2, P4);                  // gx2T

  // ---------------- cross block ----------------
  gemm_mfma<<<dim3(4, 8, 24), b256, 0, stream>>>(P4 + 8 * PL, PL, 31, WPcq, 0, 0, P2, PL,
      1024, 512, 512, 1.f, 2, nullptr, nullptr, 0, nullptr, nullptr);        // q_restT
  gemm_mfma<<<dim3(4, 8, 24), b256, 0, stream>>>(P4 + 8 * PL, PL, 31, WPcphi, 0, 0, P3, PL,
      1024, 512, 512, 1.f, 0, nullptr, nullptr, 0, nullptr, nullptr);        // phi_restT
  gemm_mfma<<<dim3(4, 8, 8), b256, 0, stream>>>(P4, PL, 31, WPck, 0, 0, P2 + 24 * PL, PL,
      1024, 512, 512, 1.f, 2, nullptr, nullptr, 0, nullptr, nullptr);        // k0T
  gemm_mfma<<<dim3(4, 8, 8), b256, 0, stream>>>(P4, PL, 31, WPcv, 0, 0, P3 + 24 * PL, PL,
      1024, 512, 512, 1.f, 0, nullptr, nullptr, 0, nullptr, nullptr);        // v0T
  gemm_mfma<<<dim3(4, 8, 8), b256, 0, stream>>>(P4, PL, 31, WPcphi, 0, 0, PHF, PL,
      1024, 512, 512, 1.f, 0, nullptr, nullptr, 0, nullptr, nullptr);        // phi_firstT
  colsum<<<dim3(2, 8), b256, 0, stream>>>(P2 + 24 * PL, PL, nullptr, QG, 1.f / 1024.f);
  rowdot<<<dim3(256, 8), b256, 0, stream>>>(P2 + 24 * PL, PL, QG, 7, SC, 0);
  softmax_row<<<8, b256, 0, stream>>>(SC, AL);
  transpose_b<<<dim3(32, 16, 8), bT, 0, stream>>>(P2 + 24 * PL, K0S, AL);  // k0'
  transpose_b<<<dim3(32, 16, 8), bT, 0, stream>>>(P3 + 24 * PL, V0S, nullptr);
  gemm_mfma<<<dim3(4, 4, 8), b256, 0, stream>>>(V0S, PL, 31, K0S, PL, 31, KV2, SZW,
      512, 512, 1024, rsc, 0, nullptr, nullptr, 0, nullptr, nullptr);
  colsum<<<dim3(2, 8), b256, 0, stream>>>(P2 + 24 * PL, PL, AL, KS, 1.f);
  rowdot<<<dim3(256, 24), b256, 0, stream>>>(P2, PL, KS, 7, ZR, 1);
  // y_restT = q_restT.kvT2[g&7] * z[n] * phi_restT  (in-place into P3)
  gemm_mfma<<<dim3(4, 8, 24), b256, 0, stream>>>(P2, PL, 31, KV2, SZW, 7, P3, PL,
      1024, 512, 512, 1.f, 0, nullptr, ZR, 1024, P3, nullptr);
  ybar_k<<<2048, b256, 0, stream>>>(P3, YB);
  hfirst_k<<<16384, b256, 0, stream>>>(P4, PHF, YB, P2 + 24 * PL);   // h_first
  ln_rows<<<8192, b256, 0, stream>>>(P2 + 24 * PL, cg1, cb1, P3 + 24 * PL, 0);
  gemm_mfma<<<dim3(16, 64, 1), b256, 0, stream>>>(P3 + 24 * PL, 0, 0, WF3, 0, 0, HID, 0,
      8192, 2048, 512, 1.f, 1, cf1b, nullptr, 0, nullptr, nullptr);
  gemm_mfma<<<dim3(4, 64, 1), b256, 0, stream>>>(HID, 0, 0, WF4, 0, 0, P2 + 24 * PL, 0,
      8192, 512, 2048, 1.f, 0, cf2b, nullptr, 0, nullptr, P3 + 24 * PL);
  ln_rows<<<8192, b256, 0, stream>>>(P2 + 24 * PL, cg2, cb2, P3 + 24 * PL, 1); // crossT
  assemble_t<<<dim3(32, 16, 32), bT, 0, stream>>>(P4, P3 + 24 * PL, (float*)d_out);
}